// Round 1
// baseline (521.282 us; speedup 1.0000x reference)
//
#include <hip/hip_runtime.h>
#include <hip/hip_bf16.h>
#include <math.h>

#define NN 262144
#define CC 512
#define BB 1024
#define EPSF 1e-5f

__device__ __forceinline__ int lower_bound_i(const int* __restrict__ a, int n, int v) {
    int lo = 0, hi = n;
    while (lo < hi) { int mid = (lo + hi) >> 1; if (a[mid] < v) lo = mid + 1; else hi = mid; }
    return lo;
}

__device__ __forceinline__ float sigmoidf(float v) { return 1.0f / (1.0f + __expf(-v)); }

// ---------------- Kernel A: per-segment pass 1 -------------------------------
// One block per segment. Lane l: g = l>>2, q = l&3, handles h = 4q..4q+3.
// Computes: seg sums/max of x_c, seg sums of x_c^2, per-node sp_gate (+tau)
// written to ws, and seg sums of out_s = (spg+tau)*x_s and its square.
__global__ void kA(const float* __restrict__ x, const int* __restrict__ batch,
                   const float* __restrict__ sweight, const float* __restrict__ sbias,
                   const float* __restrict__ gn_w, const float* __restrict__ gn_b,
                   const float* __restrict__ sp_W1, const float* __restrict__ sp_b1,
                   const float* __restrict__ sp_W2, const float* __restrict__ sp_b2,
                   const float* __restrict__ init_scale,
                   float* __restrict__ segS1, float* __restrict__ segMx,
                   float* __restrict__ segS2, float* __restrict__ segT1,
                   float* __restrict__ segT2, int* __restrict__ segCnt,
                   float* __restrict__ spgt)
{
    const int b    = blockIdx.x;
    const int tid  = threadIdx.x;
    const int lane = tid & 63;
    const int w    = tid >> 6;
    const int g    = lane >> 2;
    const int q    = lane & 3;
    const int h0   = q * 4;
    const int kk   = g & 7;

    __shared__ float red[4][5][256];

    const int s = lower_bound_i(batch, NN, b);
    const int e = lower_bound_i(batch, NN, b + 1);
    const float tau = tanhf(init_scale[0]);

    // per-lane constant preloads (registers; loop-invariant)
    float gwv[4], gbv[4], b2v[4], swv[4], sbv[4], w1m[4], w1x[4], w1s[4], w2r[4];
#pragma unroll
    for (int j = 0; j < 4; ++j) {
        const int h = h0 + j;
        gwv[j] = gn_w[g * 16 + h];
        gbv[j] = gn_b[g * 16 + h];
        b2v[j] = sp_b2[h];
        swv[j] = sweight[h];
        sbv[j] = sbias[h];
        w1m[j] = sp_W1[h * 8 + kk];
        w1x[j] = sp_W1[(16 + h) * 8 + kk];
        w1s[j] = sp_W1[(32 + h) * 8 + kk];
        w2r[j] = sp_W2[kk * 16 + h];
    }
    const float b1k = sp_b1[kk];

    float sc1[4] = {0.f,0.f,0.f,0.f}, sc2[4] = {0.f,0.f,0.f,0.f};
    float st1[4] = {0.f,0.f,0.f,0.f}, st2[4] = {0.f,0.f,0.f,0.f};
    float mxc[4] = {-INFINITY,-INFINITY,-INFINITY,-INFINITY};

    for (int n = s + w; n < e; n += 4) {
        const float* row = x + (size_t)n * CC + g * 32 + h0;
        const float4 c4 = *(const float4*)row;
        const float4 s4 = *(const float4*)(row + 16);
        float ca[4] = {c4.x, c4.y, c4.z, c4.w};
        float sa[4] = {s4.x, s4.y, s4.z, s4.w};

        // c-part accumulation (raw)
#pragma unroll
        for (int j = 0; j < 4; ++j) {
            sc1[j] += ca[j];
            sc2[j] = fmaf(ca[j], ca[j], sc2[j]);
            mxc[j] = fmaxf(mxc[j], ca[j]);
        }

        // groupnorm over h within group g (4 q-lanes, xor 1/2 = quad_perm)
        float ls = sa[0] + sa[1] + sa[2] + sa[3];
        float lq = sa[0]*sa[0] + sa[1]*sa[1] + sa[2]*sa[2] + sa[3]*sa[3];
        ls += __shfl_xor(ls, 1); ls += __shfl_xor(ls, 2);
        lq += __shfl_xor(lq, 1); lq += __shfl_xor(lq, 2);
        const float mu   = ls * 0.0625f;
        const float var  = lq * 0.0625f - mu * mu;
        const float rstd = rsqrtf(var + EPSF);
        float xn[4];
#pragma unroll
        for (int j = 0; j < 4; ++j)
            xn[j] = fmaf((sa[j] - mu) * rstd, gwv[j], gbv[j]);

        // ctx reductions over g (16 lanes stride 4: masks 4,8,16,32)
        float sm[4], mx[4];
#pragma unroll
        for (int j = 0; j < 4; ++j) { sm[j] = xn[j]; mx[j] = xn[j]; }
#pragma unroll
        for (int m = 4; m <= 32; m <<= 1) {
#pragma unroll
            for (int j = 0; j < 4; ++j) {
                sm[j] += __shfl_xor(sm[j], m);
                mx[j] = fmaxf(mx[j], __shfl_xor(mx[j], m));
            }
        }
        float mean[4], ssq[4];
#pragma unroll
        for (int j = 0; j < 4; ++j) {
            mean[j] = sm[j] * 0.0625f;
            const float d = xn[j] - mean[j];
            ssq[j] = d * d;
        }
#pragma unroll
        for (int m = 4; m <= 32; m <<= 1) {
#pragma unroll
            for (int j = 0; j < 4; ++j) ssq[j] += __shfl_xor(ssq[j], m);
        }
        float stdc[4];
#pragma unroll
        for (int j = 0; j < 4; ++j) stdc[j] = sqrtf(ssq[j] * (1.0f / 15.0f));

        // spatial MLP: lane computes partial for k = kk, reduce over q (xor1/2)
        float p = 0.f;
#pragma unroll
        for (int j = 0; j < 4; ++j) {
            p = fmaf(mean[j], w1m[j], p);
            p = fmaf(mx[j],   w1x[j], p);
            p = fmaf(stdc[j], w1s[j], p);
        }
        p += __shfl_xor(p, 1); p += __shfl_xor(p, 2);
        const float hsk = fmaxf(p + b1k, 0.0f);
        // gather sum over k (g bits 0..2 -> masks 4,8,16)
        float t[4];
#pragma unroll
        for (int j = 0; j < 4; ++j) t[j] = hsk * w2r[j];
#pragma unroll
        for (int m = 4; m <= 16; m <<= 1) {
#pragma unroll
            for (int j = 0; j < 4; ++j) t[j] += __shfl_xor(t[j], m);
        }
        float spg[4];
#pragma unroll
        for (int j = 0; j < 4; ++j)
            spg[j] = fmaf(sigmoidf(t[j] + b2v[j]), 1.0f + swv[j], sbv[j]) + tau;

        // s-part accumulation of out_s = spg*x_s
#pragma unroll
        for (int j = 0; j < 4; ++j) {
            const float os = spg[j] * sa[j];
            st1[j] += os;
            st2[j] = fmaf(os, os, st2[j]);
        }

        if (lane < 4) {
            *(float4*)(spgt + (size_t)n * 16 + h0) =
                make_float4(spg[0], spg[1], spg[2], spg[3]);
        }
    }

    // combine 4 waves via LDS
    const int ch = g * 16 + h0;
    *(float4*)&red[w][0][ch] = make_float4(sc1[0], sc1[1], sc1[2], sc1[3]);
    *(float4*)&red[w][1][ch] = make_float4(mxc[0], mxc[1], mxc[2], mxc[3]);
    *(float4*)&red[w][2][ch] = make_float4(sc2[0], sc2[1], sc2[2], sc2[3]);
    *(float4*)&red[w][3][ch] = make_float4(st1[0], st1[1], st1[2], st1[3]);
    *(float4*)&red[w][4][ch] = make_float4(st2[0], st2[1], st2[2], st2[3]);
    __syncthreads();
    if (tid < 256) {
        const int c = tid;
        float a0 = red[0][0][c] + red[1][0][c] + red[2][0][c] + red[3][0][c];
        float a1 = fmaxf(fmaxf(red[0][1][c], red[1][1][c]), fmaxf(red[2][1][c], red[3][1][c]));
        float a2 = red[0][2][c] + red[1][2][c] + red[2][2][c] + red[3][2][c];
        float a3 = red[0][3][c] + red[1][3][c] + red[2][3][c] + red[3][3][c];
        float a4 = red[0][4][c] + red[1][4][c] + red[2][4][c] + red[3][4][c];
        segS1[b * 256 + c] = a0;
        segMx[b * 256 + c] = a1;
        segS2[b * 256 + c] = a2;
        segT1[b * 256 + c] = a3;
        segT2[b * 256 + c] = a4;
    }
    if (tid == 0) segCnt[b] = e - s;
}

// ---------------- Kernel F: per-segment finalize -----------------------------
// Channel-MLP -> ch_gate; closed-form graphnorm stats -> per (seg,col) affine.
__global__ void kF(const float* __restrict__ segS1, const float* __restrict__ segMx,
                   const float* __restrict__ segS2, const float* __restrict__ segT1,
                   const float* __restrict__ segT2, const int* __restrict__ segCnt,
                   const float* __restrict__ ch_W1, const float* __restrict__ ch_b1,
                   const float* __restrict__ ch_W2, const float* __restrict__ ch_b2,
                   const float* __restrict__ cweight, const float* __restrict__ cbias,
                   const float* __restrict__ init_scale,
                   const float* __restrict__ gms, const float* __restrict__ gw,
                   const float* __restrict__ gb,
                   float* __restrict__ coef, float* __restrict__ offs)
{
    const int b = blockIdx.x;
    const int tid = threadIdx.x;
    __shared__ float gap[512];
    __shared__ float hch[64];
    __shared__ float part[4][64];

    const int cnt = segCnt[b];
    const float inv = 1.0f / (float)max(cnt, 1);
    if (tid < 256) {
        gap[tid] = segS1[b * 256 + tid] * inv;
        const float m = segMx[b * 256 + tid];
        gap[256 + tid] = (cnt > 0) ? m : 0.0f;
    }
    __syncthreads();
    {
        const int t = tid & 63, pp = tid >> 6;
        float acc = 0.f;
        for (int i = pp * 128; i < pp * 128 + 128; ++i)
            acc = fmaf(gap[i], ch_W1[i * 64 + t], acc);
        part[pp][t] = acc;
    }
    __syncthreads();
    if (tid < 64)
        hch[tid] = fmaxf(part[0][tid] + part[1][tid] + part[2][tid] + part[3][tid] + ch_b1[tid], 0.0f);
    __syncthreads();
    if (tid < 256) {
        const int c = tid, gg = c >> 4, h = c & 15;
        float acc = ch_b2[c];
        for (int k = 0; k < 64; ++k) acc = fmaf(hch[k], ch_W2[k * 256 + c], acc);
        const float chg = fmaf(sigmoidf(acc), 1.0f + cweight[h], cbias[h]);
        const float tau = tanhf(init_scale[0]);
        const float ct = chg + tau;
        const int colc = gg * 32 + h, cols = colc + 16;
        // c-column: out = ct * x_c
        {
            const float S1 = segS1[b * 256 + c], S2 = segS2[b * 256 + c];
            const float m  = ct * S1 * inv;
            const float e2 = ct * ct * S2 * inv;
            const float smv = gms[colc];
            const float gv = fmaxf(e2 - m * m * smv * (2.0f - smv), 0.0f);
            const float A  = gw[colc] * rsqrtf(gv + EPSF);
            coef[b * 512 + colc] = A * ct;
            offs[b * 512 + colc] = gb[colc] - m * smv * A;
        }
        // s-column: out = spgt(node,h) * x_s
        {
            const float T1 = segT1[b * 256 + c], T2 = segT2[b * 256 + c];
            const float m  = T1 * inv;
            const float e2 = T2 * inv;
            const float smv = gms[cols];
            const float gv = fmaxf(e2 - m * m * smv * (2.0f - smv), 0.0f);
            const float A  = gw[cols] * rsqrtf(gv + EPSF);
            coef[b * 512 + cols] = A;
            offs[b * 512 + cols] = gb[cols] - m * smv * A;
        }
    }
}

// ---------------- Kernel B: streaming final write ----------------------------
// Lanes mapped to OUTPUT positions: out[n, 4l..4l+3] and out[n, 256+4l..+3].
// Needed x cols land on 4 coalesced float2 loads; all 8 slots of a lane share
// c/s parity p0 = (l>>3)&1 and the same spgt pair.
__global__ void kB(const float* __restrict__ x, const int* __restrict__ batch,
                   const float* __restrict__ coef, const float* __restrict__ offs,
                   const float* __restrict__ spgt, float* __restrict__ out)
{
    const int b = blockIdx.x;
    const int tid = threadIdx.x;
    const int lane = tid & 63, w = tid >> 6;
    const int l2 = lane * 2;
    const int p0 = (lane >> 3) & 1;

    const int s = lower_bound_i(batch, NN, b);
    const int e = lower_bound_i(batch, NN, b + 1);

    const float* cfb = coef + (size_t)b * 512;
    const float* ofb = offs + (size_t)b * 512;
    const float cf0 = cfb[l2],       cf1 = cfb[l2 + 1];
    const float cf2 = cfb[128 + l2], cf3 = cfb[129 + l2];
    const float cf4 = cfb[256 + l2], cf5 = cfb[257 + l2];
    const float cf6 = cfb[384 + l2], cf7 = cfb[385 + l2];
    const float of0 = ofb[l2],       of1 = ofb[l2 + 1];
    const float of2 = ofb[128 + l2], of3 = ofb[129 + l2];
    const float of4 = ofb[256 + l2], of5 = ofb[257 + l2];
    const float of6 = ofb[384 + l2], of7 = ofb[385 + l2];

    for (int n = s + w; n < e; n += 4) {
        const float2* r2 = (const float2*)(x + (size_t)n * CC);
        const float2 xa = r2[lane];
        const float2 xb = r2[64 + lane];
        const float2 xc = r2[128 + lane];
        const float2 xd = r2[192 + lane];
        const float2 sp = *(const float2*)(spgt + (size_t)n * 16 + (l2 & 15));
        const float me = p0 ? sp.x : 1.0f;
        const float mo = p0 ? sp.y : 1.0f;

        const float v0 = fmaf(cf0 * me, xa.x, of0);
        const float v1 = fmaf(cf1 * mo, xa.y, of1);
        const float v2 = fmaf(cf2 * me, xb.x, of2);
        const float v3 = fmaf(cf3 * mo, xb.y, of3);
        const float v4 = fmaf(cf4 * me, xc.x, of4);
        const float v5 = fmaf(cf5 * mo, xc.y, of5);
        const float v6 = fmaf(cf6 * me, xd.x, of6);
        const float v7 = fmaf(cf7 * mo, xd.y, of7);

        float4* o4 = (float4*)(out + (size_t)n * CC);
        o4[lane]      = make_float4(v0, v4, v1, v5);
        o4[64 + lane] = make_float4(v2, v6, v3, v7);
    }
}

extern "C" void kernel_launch(void* const* d_in, const int* in_sizes, int n_in,
                              void* d_out, int out_size, void* d_ws, size_t ws_size,
                              hipStream_t stream) {
    (void)in_sizes; (void)n_in; (void)out_size; (void)ws_size;
    const float* x        = (const float*)d_in[0];
    const int*   batch    = (const int*)d_in[1];
    // d_in[2] = num_segments (hardcoded BB)
    const float* cweight  = (const float*)d_in[3];
    const float* cbias    = (const float*)d_in[4];
    const float* sweight  = (const float*)d_in[5];
    const float* sbias    = (const float*)d_in[6];
    const float* ch_W1    = (const float*)d_in[7];
    const float* ch_b1    = (const float*)d_in[8];
    const float* ch_W2    = (const float*)d_in[9];
    const float* ch_b2    = (const float*)d_in[10];
    const float* gn_w     = (const float*)d_in[11];
    const float* gn_b     = (const float*)d_in[12];
    const float* sp_W1    = (const float*)d_in[13];
    const float* sp_b1    = (const float*)d_in[14];
    const float* sp_W2    = (const float*)d_in[15];
    const float* sp_b2    = (const float*)d_in[16];
    const float* init_sc  = (const float*)d_in[17];
    const float* gnw      = (const float*)d_in[18];
    const float* gnb      = (const float*)d_in[19];
    const float* gms      = (const float*)d_in[20];

    float* ws    = (float*)d_ws;
    float* segS1 = ws;                       // BB*256
    float* segMx = segS1 + BB * 256;
    float* segS2 = segMx + BB * 256;
    float* segT1 = segS2 + BB * 256;
    float* segT2 = segT1 + BB * 256;
    int*   segCnt = (int*)(segT2 + BB * 256); // BB
    float* coef  = (float*)(segCnt + BB);     // BB*512
    float* offs  = coef + BB * 512;           // BB*512
    float* spgt  = offs + BB * 512;           // NN*16
    float* outp  = (float*)d_out;

    kA<<<BB, 256, 0, stream>>>(x, batch, sweight, sbias, gn_w, gn_b,
                               sp_W1, sp_b1, sp_W2, sp_b2, init_sc,
                               segS1, segMx, segS2, segT1, segT2, segCnt, spgt);
    kF<<<BB, 256, 0, stream>>>(segS1, segMx, segS2, segT1, segT2, segCnt,
                               ch_W1, ch_b1, ch_W2, ch_b2, cweight, cbias,
                               init_sc, gms, gnw, gnb, coef, offs);
    kB<<<BB, 256, 0, stream>>>(x, batch, coef, offs, spgt, outp);
}

// Round 3
// 484.043 us; speedup vs baseline: 1.0769x; 1.0769x over previous
//
#include <hip/hip_runtime.h>
#include <hip/hip_bf16.h>
#include <math.h>

#define NN 262144
#define CC 512
#define BB 1024
#define EPSF 1e-5f

typedef float f32x4 __attribute__((ext_vector_type(4)));

__device__ __forceinline__ int lower_bound_i(const int* __restrict__ a, int n, int v) {
    int lo = 0, hi = n;
    while (lo < hi) { int mid = (lo + hi) >> 1; if (a[mid] < v) lo = mid + 1; else hi = mid; }
    return lo;
}

__device__ __forceinline__ float sigmoidf(float v) { return 1.0f / (1.0f + __expf(-v)); }

// Single-instruction DPP reduction steps (fused v_add_f32_dpp / v_max_f32_dpp).
// ctrl: 0xB1 = quad_perm xor1, 0x4E = quad_perm xor2,
//       0x124 = row_ror:4, 0x128 = row_ror:8, 0x141 = row_half_mirror (l^7)
template<int CTRL>
__device__ __forceinline__ float dppAdd(float v) {
    int t = __builtin_amdgcn_update_dpp(0, __float_as_int(v), CTRL, 0xf, 0xf, true);
    return v + __int_as_float(t);
}
template<int CTRL>
__device__ __forceinline__ float dppMax(float v) {
    int t = __builtin_amdgcn_update_dpp(0, __float_as_int(v), CTRL, 0xf, 0xf, true);
    return fmaxf(v, __int_as_float(t));
}

// ---------------- Kernel A: per-segment pass 1 -------------------------------
// Lane map (layout B): g = lane&15 (group), q = lane>>4, handles h = 4q..4q+3.
// Ctx reductions over g are within a 16-lane DPP row -> pure VALU.
// Only groupnorm-over-h and MLP q-reduce cross rows (6 shuffles/node).
__global__ void kA(const float* __restrict__ x, const int* __restrict__ batch,
                   const float* __restrict__ sweight, const float* __restrict__ sbias,
                   const float* __restrict__ gn_w, const float* __restrict__ gn_b,
                   const float* __restrict__ sp_W1, const float* __restrict__ sp_b1,
                   const float* __restrict__ sp_W2, const float* __restrict__ sp_b2,
                   const float* __restrict__ init_scale,
                   float* __restrict__ segS1, float* __restrict__ segMx,
                   float* __restrict__ segS2, float* __restrict__ segT1,
                   float* __restrict__ segT2, int* __restrict__ segCnt,
                   float* __restrict__ spgt)
{
    const int b    = blockIdx.x;
    const int tid  = threadIdx.x;
    const int lane = tid & 63;
    const int w    = tid >> 6;
    const int g    = lane & 15;
    const int q    = lane >> 4;
    const int h0   = q * 4;
    const int kk   = g & 7;

    __shared__ float red[4][5][256];

    const int s = lower_bound_i(batch, NN, b);
    const int e = lower_bound_i(batch, NN, b + 1);
    const float tau = tanhf(init_scale[0]);

    float gwv[4], gbv[4], b2v[4], swv[4], sbv[4], w1m[4], w1x[4], w1s[4], w2r[4];
#pragma unroll
    for (int j = 0; j < 4; ++j) {
        const int h = h0 + j;
        gwv[j] = gn_w[g * 16 + h];
        gbv[j] = gn_b[g * 16 + h];
        b2v[j] = sp_b2[h];
        swv[j] = sweight[h];
        sbv[j] = sbias[h];
        w1m[j] = sp_W1[h * 8 + kk];
        w1x[j] = sp_W1[(16 + h) * 8 + kk];
        w1s[j] = sp_W1[(32 + h) * 8 + kk];
        w2r[j] = sp_W2[kk * 16 + h];
    }
    const float b1k = sp_b1[kk];

    float sc1[4] = {0.f,0.f,0.f,0.f}, sc2[4] = {0.f,0.f,0.f,0.f};
    float st1[4] = {0.f,0.f,0.f,0.f}, st2[4] = {0.f,0.f,0.f,0.f};
    float mxc[4] = {-INFINITY,-INFINITY,-INFINITY,-INFINITY};

    for (int n = s + w; n < e; n += 4) {
        const float* row = x + (size_t)n * CC + g * 32 + h0;
        const float4 c4 = *(const float4*)row;
        const float4 s4 = *(const float4*)(row + 16);
        float ca[4] = {c4.x, c4.y, c4.z, c4.w};
        float sa[4] = {s4.x, s4.y, s4.z, s4.w};

#pragma unroll
        for (int j = 0; j < 4; ++j) {
            sc1[j] += ca[j];
            sc2[j] = fmaf(ca[j], ca[j], sc2[j]);
            mxc[j] = fmaxf(mxc[j], ca[j]);
        }

        // groupnorm over h (local j + cross-row q): 4 DS shuffles
        float ls = sa[0] + sa[1] + sa[2] + sa[3];
        float lq = fmaf(sa[0], sa[0], fmaf(sa[1], sa[1], fmaf(sa[2], sa[2], sa[3] * sa[3])));
        ls += __shfl_xor(ls, 16); ls += __shfl_xor(ls, 32);
        lq += __shfl_xor(lq, 16); lq += __shfl_xor(lq, 32);
        const float mu   = ls * 0.0625f;
        const float var  = lq * 0.0625f - mu * mu;
        const float rstd = rsqrtf(var + EPSF);
        float xn[4];
#pragma unroll
        for (int j = 0; j < 4; ++j)
            xn[j] = fmaf((sa[j] - mu) * rstd, gwv[j], gbv[j]);

        // ctx sum/max over g (bits 0-3, within DPP row): 4 fused VALU each
        float sm[4], mx[4];
#pragma unroll
        for (int j = 0; j < 4; ++j) {
            float v = xn[j];
            v = dppAdd<0xB1>(v); v = dppAdd<0x4E>(v);
            v = dppAdd<0x124>(v); v = dppAdd<0x128>(v);
            sm[j] = v;
            float m = xn[j];
            m = dppMax<0xB1>(m); m = dppMax<0x4E>(m);
            m = dppMax<0x124>(m); m = dppMax<0x128>(m);
            mx[j] = m;
        }
        float mean[4], ssq[4];
#pragma unroll
        for (int j = 0; j < 4; ++j) {
            mean[j] = sm[j] * 0.0625f;
            const float d = xn[j] - mean[j];
            float v = d * d;
            v = dppAdd<0xB1>(v); v = dppAdd<0x4E>(v);
            v = dppAdd<0x124>(v); v = dppAdd<0x128>(v);
            ssq[j] = v;
        }
        float stdc[4];
#pragma unroll
        for (int j = 0; j < 4; ++j) stdc[j] = sqrtf(ssq[j] * (1.0f / 15.0f));

        // spatial MLP: partial for k = kk, reduce over q (2 DS shuffles)
        float p = 0.f;
#pragma unroll
        for (int j = 0; j < 4; ++j) {
            p = fmaf(mean[j], w1m[j], p);
            p = fmaf(mx[j],   w1x[j], p);
            p = fmaf(stdc[j], w1s[j], p);
        }
        p += __shfl_xor(p, 16); p += __shfl_xor(p, 32);
        const float hsk = fmaxf(p + b1k, 0.0f);

        // gather over k (bits 0-2 within row, bit3-half replicated): 3 DPP
        float spg[4];
#pragma unroll
        for (int j = 0; j < 4; ++j) {
            float t = hsk * w2r[j];
            t = dppAdd<0xB1>(t); t = dppAdd<0x4E>(t); t = dppAdd<0x141>(t);
            spg[j] = fmaf(sigmoidf(t + b2v[j]), 1.0f + swv[j], sbv[j]) + tau;
        }

#pragma unroll
        for (int j = 0; j < 4; ++j) {
            const float os = spg[j] * sa[j];
            st1[j] += os;
            st2[j] = fmaf(os, os, st2[j]);
        }

        if (g == 0) {
            *(float4*)(spgt + (size_t)n * 16 + h0) =
                make_float4(spg[0], spg[1], spg[2], spg[3]);
        }
    }

    const int ch = g * 16 + h0;
    *(float4*)&red[w][0][ch] = make_float4(sc1[0], sc1[1], sc1[2], sc1[3]);
    *(float4*)&red[w][1][ch] = make_float4(mxc[0], mxc[1], mxc[2], mxc[3]);
    *(float4*)&red[w][2][ch] = make_float4(sc2[0], sc2[1], sc2[2], sc2[3]);
    *(float4*)&red[w][3][ch] = make_float4(st1[0], st1[1], st1[2], st1[3]);
    *(float4*)&red[w][4][ch] = make_float4(st2[0], st2[1], st2[2], st2[3]);
    __syncthreads();
    if (tid < 256) {
        const int c = tid;
        float a0 = red[0][0][c] + red[1][0][c] + red[2][0][c] + red[3][0][c];
        float a1 = fmaxf(fmaxf(red[0][1][c], red[1][1][c]), fmaxf(red[2][1][c], red[3][1][c]));
        float a2 = red[0][2][c] + red[1][2][c] + red[2][2][c] + red[3][2][c];
        float a3 = red[0][3][c] + red[1][3][c] + red[2][3][c] + red[3][3][c];
        float a4 = red[0][4][c] + red[1][4][c] + red[2][4][c] + red[3][4][c];
        segS1[b * 256 + c] = a0;
        segMx[b * 256 + c] = a1;
        segS2[b * 256 + c] = a2;
        segT1[b * 256 + c] = a3;
        segT2[b * 256 + c] = a4;
    }
    if (tid == 0) segCnt[b] = e - s;
}

// ---------------- Kernel F: per-segment finalize -----------------------------
__global__ void kF(const float* __restrict__ segS1, const float* __restrict__ segMx,
                   const float* __restrict__ segS2, const float* __restrict__ segT1,
                   const float* __restrict__ segT2, const int* __restrict__ segCnt,
                   const float* __restrict__ ch_W1, const float* __restrict__ ch_b1,
                   const float* __restrict__ ch_W2, const float* __restrict__ ch_b2,
                   const float* __restrict__ cweight, const float* __restrict__ cbias,
                   const float* __restrict__ init_scale,
                   const float* __restrict__ gms, const float* __restrict__ gw,
                   const float* __restrict__ gb,
                   float* __restrict__ coef, float* __restrict__ offs)
{
    const int b = blockIdx.x;
    const int tid = threadIdx.x;
    __shared__ float gap[512];
    __shared__ float hch[64];
    __shared__ float part[4][64];

    const int cnt = segCnt[b];
    const float inv = 1.0f / (float)max(cnt, 1);
    if (tid < 256) {
        gap[tid] = segS1[b * 256 + tid] * inv;
        const float m = segMx[b * 256 + tid];
        gap[256 + tid] = (cnt > 0) ? m : 0.0f;
    }
    __syncthreads();
    {
        const int t = tid & 63, pp = tid >> 6;
        float acc = 0.f;
        for (int i = pp * 128; i < pp * 128 + 128; ++i)
            acc = fmaf(gap[i], ch_W1[i * 64 + t], acc);
        part[pp][t] = acc;
    }
    __syncthreads();
    if (tid < 64)
        hch[tid] = fmaxf(part[0][tid] + part[1][tid] + part[2][tid] + part[3][tid] + ch_b1[tid], 0.0f);
    __syncthreads();
    if (tid < 256) {
        const int c = tid, gg = c >> 4, h = c & 15;
        float acc = ch_b2[c];
        for (int k = 0; k < 64; ++k) acc = fmaf(hch[k], ch_W2[k * 256 + c], acc);
        const float chg = fmaf(sigmoidf(acc), 1.0f + cweight[h], cbias[h]);
        const float tau = tanhf(init_scale[0]);
        const float ct = chg + tau;
        const int colc = gg * 32 + h, cols = colc + 16;
        {
            const float S1 = segS1[b * 256 + c], S2 = segS2[b * 256 + c];
            const float m  = ct * S1 * inv;
            const float e2 = ct * ct * S2 * inv;
            const float smv = gms[colc];
            const float gv = fmaxf(e2 - m * m * smv * (2.0f - smv), 0.0f);
            const float A  = gw[colc] * rsqrtf(gv + EPSF);
            coef[b * 512 + colc] = A * ct;
            offs[b * 512 + colc] = gb[colc] - m * smv * A;
        }
        {
            const float T1 = segT1[b * 256 + c], T2 = segT2[b * 256 + c];
            const float m  = T1 * inv;
            const float e2 = T2 * inv;
            const float smv = gms[cols];
            const float gv = fmaxf(e2 - m * m * smv * (2.0f - smv), 0.0f);
            const float A  = gw[cols] * rsqrtf(gv + EPSF);
            coef[b * 512 + cols] = A;
            offs[b * 512 + cols] = gb[cols] - m * smv * A;
        }
    }
}

// ---------------- Kernel B: streaming final write ----------------------------
// Segments processed in REVERSE so kA's tail of x is still L3-resident.
// Output stores are nontemporal so 512 MB of writes don't evict x from L3.
__global__ void kB(const float* __restrict__ x, const int* __restrict__ batch,
                   const float* __restrict__ coef, const float* __restrict__ offs,
                   const float* __restrict__ spgt, float* __restrict__ out)
{
    const int b = BB - 1 - blockIdx.x;
    const int tid = threadIdx.x;
    const int lane = tid & 63, w = tid >> 6;
    const int l2 = lane * 2;
    const int p0 = (lane >> 3) & 1;

    const int s = lower_bound_i(batch, NN, b);
    const int e = lower_bound_i(batch, NN, b + 1);

    const float* cfb = coef + (size_t)b * 512;
    const float* ofb = offs + (size_t)b * 512;
    const float cf0 = cfb[l2],       cf1 = cfb[l2 + 1];
    const float cf2 = cfb[128 + l2], cf3 = cfb[129 + l2];
    const float cf4 = cfb[256 + l2], cf5 = cfb[257 + l2];
    const float cf6 = cfb[384 + l2], cf7 = cfb[385 + l2];
    const float of0 = ofb[l2],       of1 = ofb[l2 + 1];
    const float of2 = ofb[128 + l2], of3 = ofb[129 + l2];
    const float of4 = ofb[256 + l2], of5 = ofb[257 + l2];
    const float of6 = ofb[384 + l2], of7 = ofb[385 + l2];

    for (int n = s + w; n < e; n += 4) {
        const float2* r2 = (const float2*)(x + (size_t)n * CC);
        const float2 xa = r2[lane];
        const float2 xb = r2[64 + lane];
        const float2 xc = r2[128 + lane];
        const float2 xd = r2[192 + lane];
        const float2 sp = *(const float2*)(spgt + (size_t)n * 16 + (l2 & 15));
        const float me = p0 ? sp.x : 1.0f;
        const float mo = p0 ? sp.y : 1.0f;

        const float v0 = fmaf(cf0 * me, xa.x, of0);
        const float v1 = fmaf(cf1 * mo, xa.y, of1);
        const float v2 = fmaf(cf2 * me, xb.x, of2);
        const float v3 = fmaf(cf3 * mo, xb.y, of3);
        const float v4 = fmaf(cf4 * me, xc.x, of4);
        const float v5 = fmaf(cf5 * mo, xc.y, of5);
        const float v6 = fmaf(cf6 * me, xd.x, of6);
        const float v7 = fmaf(cf7 * mo, xd.y, of7);

        f32x4* o4 = (f32x4*)(out + (size_t)n * CC);
        f32x4 pa = {v0, v4, v1, v5};
        f32x4 pb = {v2, v6, v3, v7};
        __builtin_nontemporal_store(pa, &o4[lane]);
        __builtin_nontemporal_store(pb, &o4[64 + lane]);
    }
}

extern "C" void kernel_launch(void* const* d_in, const int* in_sizes, int n_in,
                              void* d_out, int out_size, void* d_ws, size_t ws_size,
                              hipStream_t stream) {
    (void)in_sizes; (void)n_in; (void)out_size; (void)ws_size;
    const float* x        = (const float*)d_in[0];
    const int*   batch    = (const int*)d_in[1];
    const float* cweight  = (const float*)d_in[3];
    const float* cbias    = (const float*)d_in[4];
    const float* sweight  = (const float*)d_in[5];
    const float* sbias    = (const float*)d_in[6];
    const float* ch_W1    = (const float*)d_in[7];
    const float* ch_b1    = (const float*)d_in[8];
    const float* ch_W2    = (const float*)d_in[9];
    const float* ch_b2    = (const float*)d_in[10];
    const float* gn_w     = (const float*)d_in[11];
    const float* gn_b     = (const float*)d_in[12];
    const float* sp_W1    = (const float*)d_in[13];
    const float* sp_b1    = (const float*)d_in[14];
    const float* sp_W2    = (const float*)d_in[15];
    const float* sp_b2    = (const float*)d_in[16];
    const float* init_sc  = (const float*)d_in[17];
    const float* gnw      = (const float*)d_in[18];
    const float* gnb      = (const float*)d_in[19];
    const float* gms      = (const float*)d_in[20];

    float* ws    = (float*)d_ws;
    float* segS1 = ws;                        // BB*256
    float* segMx = segS1 + BB * 256;
    float* segS2 = segMx + BB * 256;
    float* segT1 = segS2 + BB * 256;
    float* segT2 = segT1 + BB * 256;
    int*   segCnt = (int*)(segT2 + BB * 256); // BB
    float* coef  = (float*)(segCnt + BB);     // BB*512
    float* offs  = coef + BB * 512;           // BB*512
    float* spgt  = offs + BB * 512;           // NN*16
    float* outp  = (float*)d_out;

    kA<<<BB, 256, 0, stream>>>(x, batch, sweight, sbias, gn_w, gn_b,
                               sp_W1, sp_b1, sp_W2, sp_b2, init_sc,
                               segS1, segMx, segS2, segT1, segT2, segCnt, spgt);
    kF<<<BB, 256, 0, stream>>>(segS1, segMx, segS2, segT1, segT2, segCnt,
                               ch_W1, ch_b1, ch_W2, ch_b2, cweight, cbias,
                               init_sc, gms, gnw, gnb, coef, offs);
    kB<<<BB, 256, 0, stream>>>(x, batch, coef, offs, spgt, outp);
}